// Round 10
// baseline (692.781 us; speedup 1.0000x reference)
//
#include <hip/hip_runtime.h>
#include <hip/hip_bf16.h>

// GAT (3-layer, HEADS=4, HID=32, concat=False head-mean) + global mean pool + MLP.
// R10 = R9 with the self-loop double-count fixed: c0/c1 start at zero and the
//     self contribution is added ONCE, after the ^32 slot reduce (R9 initialized
//     both slots with it -> counted twice after the reduce).
// Aggregate: 32 lanes = one 128B fp8 row (1 dword = 4ch per lane), slot=l>>5 ->
//     2 edges/load-iter, unroll 8; each lane recomputes (src, pe) locally
//     (broadcast-coalesced csr/asrc loads); zero cross-lane ops in the hot loop.

#define HEADS 4
#define HID 32
#define F_HID 128   // HEADS*HID
#define NEG_SLOPE 0.2f
#define BSHIFT 5
#define MAXB 3328   // max buckets supported (n <= 106496)

typedef float v2f __attribute__((ext_vector_type(2)));

__device__ __forceinline__ float lrelu(float v) { return v > 0.f ? v : NEG_SLOPE * v; }

__device__ __forceinline__ v2f vshflxor(v2f v, int m) {
    v2f r; r.x = __shfl_xor(v.x, m); r.y = __shfl_xor(v.y, m); return r;
}

// ---------------- CSR build ----------------

__global__ void deg_hist(const int* __restrict__ ei, int E, int* __restrict__ deg) {
    int i = blockIdx.x * blockDim.x + threadIdx.x;
    if (i < E) {
        int d = ei[E + i];          // dst row of edge_index
        atomicAdd(&deg[d], 1);
    }
}

__global__ void scan_partial(const int* __restrict__ deg, int n, int* __restrict__ partial) {
    __shared__ int sm[256];
    int t = threadIdx.x;
    int i = blockIdx.x * 256 + t;
    sm[t] = (i < n) ? deg[i] : 0;
    __syncthreads();
    for (int s = 128; s > 0; s >>= 1) {
        if (t < s) sm[t] += sm[t + s];
        __syncthreads();
    }
    if (t == 0) partial[blockIdx.x] = sm[0];
}

__global__ __launch_bounds__(512) void scan_exclusive(int* partial, int B) {
    __shared__ int sm[512];
    int t = threadIdx.x;
    int carry = 0;
    for (int base = 0; base < B; base += 512) {
        int v = (base + t < B) ? partial[base + t] : 0;
        sm[t] = v;
        __syncthreads();
        for (int s = 1; s < 512; s <<= 1) {
            int add = (t >= s) ? sm[t - s] : 0;
            __syncthreads();
            sm[t] += add;
            __syncthreads();
        }
        if (base + t < B) partial[base + t] = carry + sm[t] - v;
        carry += sm[511];
        __syncthreads();
    }
}

__global__ void scan_final(const int* __restrict__ deg, int n, const int* __restrict__ partial,
                           int* __restrict__ row_start, int* __restrict__ gcursor) {
    __shared__ int sm[256];
    int t = threadIdx.x;
    int i = blockIdx.x * 256 + t;
    int v = (i < n) ? deg[i] : 0;
    sm[t] = v;
    __syncthreads();
    for (int s = 1; s < 256; s <<= 1) {
        int add = (t >= s) ? sm[t - s] : 0;
        __syncthreads();
        sm[t] += add;
        __syncthreads();
    }
    if (i < n) {
        int excl = partial[blockIdx.x] + sm[t] - v;
        row_start[i] = excl;
        if ((i & 31) == 0) gcursor[i >> BSHIFT] = excl;   // bucket cursor seed
    }
}

// Phase B: scatter edges into 32-node buckets; per-block contiguous runs.
__global__ __launch_bounds__(512) void bucket_scatter(const int* __restrict__ ei, int E, int nb,
                                                      int* __restrict__ gcursor,
                                                      uint32_t* __restrict__ tmp) {
    __shared__ int hist[MAXB];
    __shared__ int base[MAXB];
    int t = threadIdx.x;
    int per = (E + gridDim.x - 1) / gridDim.x;
    int e0 = blockIdx.x * per;
    int e1 = e0 + per; if (e1 > E) e1 = E;

    for (int i = t; i < nb; i += 512) hist[i] = 0;
    __syncthreads();
    for (int i = e0 + t; i < e1; i += 512) {
        int d = ei[E + i];
        atomicAdd(&hist[d >> BSHIFT], 1);
    }
    __syncthreads();
    for (int i = t; i < nb; i += 512) {
        int c = hist[i];
        base[i] = c ? atomicAdd(&gcursor[i], c) : 0;
        hist[i] = 0;   // reuse as local cursor
    }
    __syncthreads();
    for (int i = e0 + t; i < e1; i += 512) {
        int d = ei[E + i];
        int s = ei[i];
        int b = d >> BSHIFT;
        int loc = atomicAdd(&hist[b], 1);
        tmp[base[b] + loc] = ((uint32_t)s << BSHIFT) | (uint32_t)(d & 31);
    }
}

// Phase C: per-bucket exact placement (positions seeded from row_start — no recount).
__global__ __launch_bounds__(256) void bucket_sort(const uint32_t* __restrict__ tmp,
                                                   const int* __restrict__ row_start,
                                                   int n, int E,
                                                   int* __restrict__ csr) {
    __shared__ int cur[32];
    int b = blockIdx.x;
    int node0 = b << BSHIFT;
    int base = row_start[node0];
    int node1 = node0 + 32;
    int end = (node1 < n) ? row_start[node1] : E;
    int cnt = end - base;
    int t = threadIdx.x;
    if (t < 32) {
        int nd = node0 + t;
        cur[t] = (nd < n) ? (row_start[nd] - base) : 0;
    }
    __syncthreads();
    for (int i = t; i < cnt; i += 256) {
        uint32_t v = tmp[base + i];
        int pos = atomicAdd(&cur[v & 31], 1);
        csr[base + pos] = (int)(v >> BSHIFT);
    }
}

// ---------------- per-layer kernels ----------------

// h = x @ W ([N,FIN] @ [FIN,128]) with fused alpha epilogue; h written as fp8 e4m3.
template <int FIN>
__global__ __launch_bounds__(256) void gemm_h(const float* __restrict__ x,
                                              const float* __restrict__ W,
                                              const float* __restrict__ a_s,
                                              const float* __restrict__ a_d,
                                              unsigned short* __restrict__ h8,
                                              float* __restrict__ asrc,
                                              float* __restrict__ adst, int n) {
    constexpr int NPB = 32;
    __shared__ float xs[NPB * FIN];
    int t = threadIdx.x;
    int base = blockIdx.x * NPB;
    int nn = n - base; if (nn > NPB) nn = NPB;

    {   // stage x tile (float4)
        const float4* xg = (const float4*)(x + (size_t)base * FIN);
        float4* xs4 = (float4*)xs;
        int tot4 = nn * FIN / 4;
        for (int i = t; i < tot4; i += 256) xs4[i] = xg[i];
        for (int i = tot4 * 4 + t; i < NPB * FIN; i += 256) xs[i] = 0.f;
    }
    __syncthreads();

    int grp = t >> 6;       // 0..3, each grp = one wave, 8 nodes
    int l = t & 63;
    int col0 = l * 2;

    float2 acc[8];
#pragma unroll
    for (int j = 0; j < 8; j++) { acc[j].x = 0.f; acc[j].y = 0.f; }

    for (int k4 = 0; k4 < FIN; k4 += 4) {
        float4 xv[8];
#pragma unroll
        for (int j = 0; j < 8; j++)
            xv[j] = *(const float4*)&xs[(grp * 8 + j) * FIN + k4];
#pragma unroll
        for (int kk = 0; kk < 4; kk++) {
            float2 wv = *(const float2*)&W[(size_t)(k4 + kk) * F_HID + col0];
#pragma unroll
            for (int j = 0; j < 8; j++) {
                float xk = (&xv[j].x)[kk];
                acc[j].x += xk * wv.x;
                acc[j].y += xk * wv.y;
            }
        }
    }

    float ws0 = a_s[col0], ws1 = a_s[col0 + 1];
    float wd0 = a_d[col0], wd1 = a_d[col0 + 1];
#pragma unroll
    for (int j = 0; j < 8; j++) {
        int node = base + grp * 8 + j;
        bool ok = node < n;
        if (ok) {
            int p8 = __builtin_amdgcn_cvt_pk_fp8_f32(acc[j].x, acc[j].y, 0, false);
            h8[((size_t)node << 6) + l] = (unsigned short)p8;
        }
        float vs = acc[j].x * ws0 + acc[j].y * ws1;
        float vd = acc[j].x * wd0 + acc[j].y * wd1;
#pragma unroll
        for (int off = 8; off >= 1; off >>= 1) {
            vs += __shfl_xor(vs, off);
            vd += __shfl_xor(vd, off);
        }
        if (ok && (l & 15) == 0) {
            int hd = l >> 4;
            asrc[node * HEADS + hd] = vs;
            adst[node * HEADS + hd] = vd;
        }
    }
}

// Wave-per-node aggregate, fp8 rows, no cross-lane ops in the loop.
// lane l: i = l&31 (dword of the 128B row -> channels 4i..4i+3), slot = l>>5,
// head hh = i>>3. Edge j = j0 + 2q + slot; each lane loads csr/asrc itself
// (broadcast-coalesced), computes pe locally, accumulates its 4 channels.
__global__ __launch_bounds__(256) void aggregate(const uint32_t* __restrict__ hb,
                                                 const float* __restrict__ asrc,
                                                 const float* __restrict__ adst,
                                                 const int* __restrict__ row_start,
                                                 const int* __restrict__ deg,
                                                 const int* __restrict__ csr_src,
                                                 const float* __restrict__ bias,
                                                 float* __restrict__ xout, int n) {
    int d = blockIdx.x * 4 + (threadIdx.x >> 6);
    if (d >= n) return;
    int l = threadIdx.x & 63;
    int i = l & 31;                  // dword index within row
    int slot = l >> 5;               // 0/1: which edge of the pair
    int hh = i >> 3;                 // head of channels 4i..4i+3

    int start = row_start[d];
    int cnt = deg[d];
    float ad = adst[d * HEADS + hh];
    float ps = __expf(lrelu(asrc[d * HEADS + hh] + ad));   // self-loop weight

    // self row load issued early; contribution added once AFTER the slot reduce
    uint32_t us = hb[((size_t)d << 5) + i];

    v2f c0 = {0.f, 0.f}, c1 = {0.f, 0.f};
    float dsum = 0.f;

    const int* csr = csr_src + start;
    for (int j0 = 0; j0 < cnt; j0 += 16) {
#pragma unroll
        for (int q = 0; q < 8; q++) {
            int j = j0 + 2 * q + slot;
            int jc = j < cnt - 1 ? j : cnt - 1;    // clamp (dup loads hit L1)
            int s = csr[jc];
            float a = asrc[s * HEADS + hh];
            uint32_t u = hb[((size_t)s << 5) + i];
            float pe = j < cnt ? __expf(lrelu(a + ad)) : 0.f;
            dsum += pe;
            v2f p2 = {pe, pe};
            c0 += p2 * __builtin_amdgcn_cvt_pk_f32_fp8((int)u, false);
            c1 += p2 * __builtin_amdgcn_cvt_pk_f32_fp8((int)u, true);
        }
    }

    // reduce the two edge-slots
    dsum += __shfl_xor(dsum, 32);
    c0 += vshflxor(c0, 32);
    c1 += vshflxor(c1, 32);

    // self-loop contribution (exactly once), then normalize
    v2f ps2 = {ps, ps};
    c0 += ps2 * __builtin_amdgcn_cvt_pk_f32_fp8((int)us, false);
    c1 += ps2 * __builtin_amdgcn_cvt_pk_f32_fp8((int)us, true);

    float inv = 1.f / (dsum + ps + 1e-16f);
    v2f iv2 = {inv, inv};
    c0 *= iv2;
    c1 *= iv2;

    // head mean: head lives in bits 3,4 of i -> lanes ^8, ^16
    c0 += vshflxor(c0, 8); c0 += vshflxor(c0, 16);
    c1 += vshflxor(c1, 8); c1 += vshflxor(c1, 16);

    if (l < 8) {   // lane i<8 holds mean channels 4i..4i+3
        float4 b4 = *(const float4*)&bias[i * 4];
        float4 ov;
        ov.x = 0.25f * c0.x + b4.x;
        ov.y = 0.25f * c0.y + b4.y;
        ov.z = 0.25f * c1.x + b4.z;
        ov.w = 0.25f * c1.y + b4.w;
        ov.x = ov.x > 0.f ? ov.x : 0.f;
        ov.y = ov.y > 0.f ? ov.y : 0.f;
        ov.z = ov.z > 0.f ? ov.z : 0.f;
        ov.w = ov.w > 0.f ? ov.w : 0.f;
        *(float4*)&xout[(size_t)d * HID + i * 4] = ov;
    }
}

// ---------------- pooling + MLP ----------------

__global__ void pool_sum(const float* __restrict__ x, int n, float* __restrict__ g) {
    __shared__ float sm[256];
    int t = threadIdx.x;
    int c = t & 31;
    int r = t >> 5;   // 8 node-rows per block
    float acc = 0.f;
    for (int i = blockIdx.x * 8 + r; i < n; i += gridDim.x * 8)
        acc += x[(size_t)i * HID + c];
    sm[t] = acc;
    __syncthreads();
    if (t < 32) {
        float v = 0.f;
#pragma unroll
        for (int k = 0; k < 8; k++) v += sm[t + 32 * k];
        atomicAdd(&g[t], v);
    }
}

__global__ void mlp_final(const float* __restrict__ g,
                          const float* __restrict__ lw1, const float* __restrict__ lb1,
                          const float* __restrict__ lw2, const float* __restrict__ lb2,
                          float* __restrict__ out, float invn) {
    __shared__ float gm[32];
    int t = threadIdx.x;
    if (t < 32) gm[t] = g[t] * invn;
    __syncthreads();
    float q = 0.f;
    if (t < 16) {
        q = lb1[t];
        for (int c = 0; c < 32; c++) q += gm[c] * lw1[c * 16 + t];
        q = q > 0.f ? q : 0.f;
        q *= lw2[t];
    }
#pragma unroll
    for (int off = 8; off >= 1; off >>= 1) q += __shfl_xor(q, off);
    if (t == 0) out[0] = q + lb2[0];
}

// ---------------- launch ----------------

extern "C" void kernel_launch(void* const* d_in, const int* in_sizes, int n_in,
                              void* d_out, int out_size, void* d_ws, size_t ws_size,
                              hipStream_t stream) {
    const float* x   = (const float*)d_in[0];
    const int*   ei  = (const int*)d_in[1];
    const float* W1  = (const float*)d_in[2];
    const float* as1 = (const float*)d_in[3];
    const float* ad1 = (const float*)d_in[4];
    const float* b1  = (const float*)d_in[5];
    const float* W2  = (const float*)d_in[6];
    const float* as2 = (const float*)d_in[7];
    const float* ad2 = (const float*)d_in[8];
    const float* b2  = (const float*)d_in[9];
    const float* W3  = (const float*)d_in[10];
    const float* as3 = (const float*)d_in[11];
    const float* ad3 = (const float*)d_in[12];
    const float* b3  = (const float*)d_in[13];
    const float* lw1 = (const float*)d_in[14];
    const float* lb1 = (const float*)d_in[15];
    const float* lw2 = (const float*)d_in[16];
    const float* lb2 = (const float*)d_in[17];
    float* out = (float*)d_out;

    int n = in_sizes[0] / 128;   // 100000
    int E = in_sizes[1] / 2;     // 1600000
    int B = (n + 255) / 256;
    int nb = (n + 31) >> BSHIFT; // 3125 buckets

    // workspace carve (256B aligned)
    char* p = (char*)d_ws;
    auto alloc = [&](size_t bytes) -> void* {
        void* r = (void*)p;
        p += (bytes + 255) & ~(size_t)255;
        return r;
    };
    int* deg       = (int*)alloc((size_t)n * 4);
    int* row_start = (int*)alloc((size_t)n * 4);
    int* gcursor   = (int*)alloc((size_t)nb * 4);
    int* partial   = (int*)alloc((size_t)B * 4);
    int* csr       = (int*)alloc((size_t)E * 4);
    uint32_t* tmp  = (uint32_t*)alloc((size_t)E * 4);
    float* asrc    = (float*)alloc((size_t)n * HEADS * 4);
    float* adst    = (float*)alloc((size_t)n * HEADS * 4);
    unsigned short* h8 = (unsigned short*)alloc((size_t)n * 64 * 2);  // fp8 rows (128B)
    float* xA      = (float*)alloc((size_t)n * HID * 4);
    float* xB      = (float*)alloc((size_t)n * HID * 4);
    float* g       = (float*)alloc(32 * 4);

    // CSR build (shared across all 3 layers)
    hipMemsetAsync(deg, 0, (size_t)n * 4, stream);
    deg_hist<<<(E + 255) / 256, 256, 0, stream>>>(ei, E, deg);
    scan_partial<<<B, 256, 0, stream>>>(deg, n, partial);
    scan_exclusive<<<1, 512, 0, stream>>>(partial, B);
    scan_final<<<B, 256, 0, stream>>>(deg, n, partial, row_start, gcursor);
    bucket_scatter<<<64, 512, 0, stream>>>(ei, E, nb, gcursor, tmp);
    bucket_sort<<<nb, 256, 0, stream>>>(tmp, row_start, n, E, csr);

    int gb = (n + 31) / 32;
    int ggb = (n + 3) / 4;

    // layer 1
    gemm_h<128><<<gb, 256, 0, stream>>>(x, W1, as1, ad1, h8, asrc, adst, n);
    aggregate<<<ggb, 256, 0, stream>>>((const uint32_t*)h8, asrc, adst, row_start, deg, csr, b1, xA, n);

    // layer 2
    gemm_h<32><<<gb, 256, 0, stream>>>(xA, W2, as2, ad2, h8, asrc, adst, n);
    aggregate<<<ggb, 256, 0, stream>>>((const uint32_t*)h8, asrc, adst, row_start, deg, csr, b2, xB, n);

    // layer 3
    gemm_h<32><<<gb, 256, 0, stream>>>(xB, W3, as3, ad3, h8, asrc, adst, n);
    aggregate<<<ggb, 256, 0, stream>>>((const uint32_t*)h8, asrc, adst, row_start, deg, csr, b3, xA, n);

    // pooling + MLP
    hipMemsetAsync(g, 0, 32 * 4, stream);
    pool_sum<<<256, 256, 0, stream>>>(xA, n, g);
    mlp_final<<<1, 64, 0, stream>>>(g, lw1, lb1, lw2, lb2, out, 1.0f / (float)n);
}

// Round 11
// 593.053 us; speedup vs baseline: 1.1682x; 1.1682x over previous
//
#include <hip/hip_runtime.h>
#include <hip/hip_bf16.h>

// GAT (3-layer, HEADS=4, HID=32, concat=False head-mean) + global mean pool + MLP.
// R11: revert aggregate to the measured-best R6 structure (bf16 256B rows,
//     4-edges-per-dwordx4 gather, bpermute broadcast) with 2 changes:
//     (a) 32-edge chunks -> 8 independent row-loads in flight (2x R6's MLP),
//     (b) no online max (shift-invariance validated in R8/R10) -> no serial
//         max-reduce/rescale chain; branchless clamped csr loads.

#define HEADS 4
#define HID 32
#define F_HID 128   // HEADS*HID
#define NEG_SLOPE 0.2f
#define BSHIFT 5
#define MAXB 3328   // max buckets supported (n <= 106496)

typedef float v2f __attribute__((ext_vector_type(2)));

__device__ __forceinline__ float lrelu(float v) { return v > 0.f ? v : NEG_SLOPE * v; }

__device__ __forceinline__ uint32_t bf16_rne(float f) {
    union { float f; uint32_t u; } c; c.f = f;
    return (c.u + 0x7fffu + ((c.u >> 16) & 1u)) >> 16;
}
__device__ __forceinline__ v2f up2(uint32_t u) {
    v2f r;
    r.x = __uint_as_float(u << 16);
    r.y = __uint_as_float(u & 0xffff0000u);
    return r;
}
__device__ __forceinline__ float bperm_f(int addr, float v) {
    return __int_as_float(__builtin_amdgcn_ds_bpermute(addr, __float_as_int(v)));
}
__device__ __forceinline__ int bperm_i(int addr, int v) {
    return __builtin_amdgcn_ds_bpermute(addr, v);
}
__device__ __forceinline__ v2f vshflxor(v2f v, int m) {
    v2f r; r.x = __shfl_xor(v.x, m); r.y = __shfl_xor(v.y, m); return r;
}

// ---------------- CSR build ----------------

__global__ void deg_hist(const int* __restrict__ ei, int E, int* __restrict__ deg) {
    int i = blockIdx.x * blockDim.x + threadIdx.x;
    if (i < E) {
        int d = ei[E + i];          // dst row of edge_index
        atomicAdd(&deg[d], 1);
    }
}

__global__ void scan_partial(const int* __restrict__ deg, int n, int* __restrict__ partial) {
    __shared__ int sm[256];
    int t = threadIdx.x;
    int i = blockIdx.x * 256 + t;
    sm[t] = (i < n) ? deg[i] : 0;
    __syncthreads();
    for (int s = 128; s > 0; s >>= 1) {
        if (t < s) sm[t] += sm[t + s];
        __syncthreads();
    }
    if (t == 0) partial[blockIdx.x] = sm[0];
}

__global__ __launch_bounds__(512) void scan_exclusive(int* partial, int B) {
    __shared__ int sm[512];
    int t = threadIdx.x;
    int carry = 0;
    for (int base = 0; base < B; base += 512) {
        int v = (base + t < B) ? partial[base + t] : 0;
        sm[t] = v;
        __syncthreads();
        for (int s = 1; s < 512; s <<= 1) {
            int add = (t >= s) ? sm[t - s] : 0;
            __syncthreads();
            sm[t] += add;
            __syncthreads();
        }
        if (base + t < B) partial[base + t] = carry + sm[t] - v;
        carry += sm[511];
        __syncthreads();
    }
}

__global__ void scan_final(const int* __restrict__ deg, int n, const int* __restrict__ partial,
                           int* __restrict__ row_start, int* __restrict__ gcursor) {
    __shared__ int sm[256];
    int t = threadIdx.x;
    int i = blockIdx.x * 256 + t;
    int v = (i < n) ? deg[i] : 0;
    sm[t] = v;
    __syncthreads();
    for (int s = 1; s < 256; s <<= 1) {
        int add = (t >= s) ? sm[t - s] : 0;
        __syncthreads();
        sm[t] += add;
        __syncthreads();
    }
    if (i < n) {
        int excl = partial[blockIdx.x] + sm[t] - v;
        row_start[i] = excl;
        if ((i & 31) == 0) gcursor[i >> BSHIFT] = excl;   // bucket cursor seed
    }
}

// Phase B: scatter edges into 32-node buckets; per-block contiguous runs.
__global__ __launch_bounds__(512) void bucket_scatter(const int* __restrict__ ei, int E, int nb,
                                                      int* __restrict__ gcursor,
                                                      uint32_t* __restrict__ tmp) {
    __shared__ int hist[MAXB];
    __shared__ int base[MAXB];
    int t = threadIdx.x;
    int per = (E + gridDim.x - 1) / gridDim.x;
    int e0 = blockIdx.x * per;
    int e1 = e0 + per; if (e1 > E) e1 = E;

    for (int i = t; i < nb; i += 512) hist[i] = 0;
    __syncthreads();
    for (int i = e0 + t; i < e1; i += 512) {
        int d = ei[E + i];
        atomicAdd(&hist[d >> BSHIFT], 1);
    }
    __syncthreads();
    for (int i = t; i < nb; i += 512) {
        int c = hist[i];
        base[i] = c ? atomicAdd(&gcursor[i], c) : 0;
        hist[i] = 0;   // reuse as local cursor
    }
    __syncthreads();
    for (int i = e0 + t; i < e1; i += 512) {
        int d = ei[E + i];
        int s = ei[i];
        int b = d >> BSHIFT;
        int loc = atomicAdd(&hist[b], 1);
        tmp[base[b] + loc] = ((uint32_t)s << BSHIFT) | (uint32_t)(d & 31);
    }
}

// Phase C: per-bucket exact placement (positions seeded from row_start — no recount).
__global__ __launch_bounds__(256) void bucket_sort(const uint32_t* __restrict__ tmp,
                                                   const int* __restrict__ row_start,
                                                   int n, int E,
                                                   int* __restrict__ csr) {
    __shared__ int cur[32];
    int b = blockIdx.x;
    int node0 = b << BSHIFT;
    int base = row_start[node0];
    int node1 = node0 + 32;
    int end = (node1 < n) ? row_start[node1] : E;
    int cnt = end - base;
    int t = threadIdx.x;
    if (t < 32) {
        int nd = node0 + t;
        cur[t] = (nd < n) ? (row_start[nd] - base) : 0;
    }
    __syncthreads();
    for (int i = t; i < cnt; i += 256) {
        uint32_t v = tmp[base + i];
        int pos = atomicAdd(&cur[v & 31], 1);
        csr[base + pos] = (int)(v >> BSHIFT);
    }
}

// ---------------- per-layer kernels ----------------

// h = x @ W ([N,FIN] @ [FIN,128]) with fused alpha epilogue; h written as bf16x2.
template <int FIN>
__global__ __launch_bounds__(256) void gemm_h(const float* __restrict__ x,
                                              const float* __restrict__ W,
                                              const float* __restrict__ a_s,
                                              const float* __restrict__ a_d,
                                              uint32_t* __restrict__ hb,
                                              float* __restrict__ asrc,
                                              float* __restrict__ adst, int n) {
    constexpr int NPB = 32;
    __shared__ float xs[NPB * FIN];
    int t = threadIdx.x;
    int base = blockIdx.x * NPB;
    int nn = n - base; if (nn > NPB) nn = NPB;

    {   // stage x tile (float4)
        const float4* xg = (const float4*)(x + (size_t)base * FIN);
        float4* xs4 = (float4*)xs;
        int tot4 = nn * FIN / 4;
        for (int i = t; i < tot4; i += 256) xs4[i] = xg[i];
        for (int i = tot4 * 4 + t; i < NPB * FIN; i += 256) xs[i] = 0.f;
    }
    __syncthreads();

    int grp = t >> 6;       // 0..3, each grp = one wave, 8 nodes
    int l = t & 63;
    int col0 = l * 2;

    float2 acc[8];
#pragma unroll
    for (int j = 0; j < 8; j++) { acc[j].x = 0.f; acc[j].y = 0.f; }

    for (int k4 = 0; k4 < FIN; k4 += 4) {
        float4 xv[8];
#pragma unroll
        for (int j = 0; j < 8; j++)
            xv[j] = *(const float4*)&xs[(grp * 8 + j) * FIN + k4];
#pragma unroll
        for (int kk = 0; kk < 4; kk++) {
            float2 wv = *(const float2*)&W[(size_t)(k4 + kk) * F_HID + col0];
#pragma unroll
            for (int j = 0; j < 8; j++) {
                float xk = (&xv[j].x)[kk];
                acc[j].x += xk * wv.x;
                acc[j].y += xk * wv.y;
            }
        }
    }

    float ws0 = a_s[col0], ws1 = a_s[col0 + 1];
    float wd0 = a_d[col0], wd1 = a_d[col0 + 1];
#pragma unroll
    for (int j = 0; j < 8; j++) {
        int node = base + grp * 8 + j;
        bool ok = node < n;
        if (ok)
            hb[((size_t)node << 6) + l] = bf16_rne(acc[j].x) | (bf16_rne(acc[j].y) << 16);
        float vs = acc[j].x * ws0 + acc[j].y * ws1;
        float vd = acc[j].x * wd0 + acc[j].y * wd1;
#pragma unroll
        for (int off = 8; off >= 1; off >>= 1) {
            vs += __shfl_xor(vs, off);
            vd += __shfl_xor(vd, off);
        }
        if (ok && (l & 15) == 0) {
            int hd = l >> 4;
            asrc[node * HEADS + hd] = vs;
            adst[node * HEADS + hd] = vd;
        }
    }
}

// Wave-per-node aggregate over bf16x2 h (256B rows), no online max.
// Edge phase: lane = hd(l>>4) x edge-slot ci(l&15); 32-edge chunks (2 per lane).
// Gather phase: edge e=l>>4 within quad, head hh=(l&15)>>2, quad kk=l&3;
//   16-lane group covers one full 256B row; 8 independent dwordx4 row-loads
//   per chunk issued before any dependent math (2x R6's loads in flight).
__global__ __launch_bounds__(256) void aggregate(const uint32_t* __restrict__ hb,
                                                 const float* __restrict__ asrc,
                                                 const float* __restrict__ adst,
                                                 const int* __restrict__ row_start,
                                                 const int* __restrict__ deg,
                                                 const int* __restrict__ csr_src,
                                                 const float* __restrict__ bias,
                                                 float* __restrict__ xout, int n) {
    int d = blockIdx.x * 4 + (threadIdx.x >> 6);
    if (d >= n) return;
    int l = threadIdx.x & 63;
    int hd = l >> 4;                 // edge-phase head
    int ci = l & 15;                 // edge-phase edge slot
    int hh = (l & 15) >> 2;          // gather-phase head
    int permH = hh << 6;             // bperm addr of lane hh*16
    int permb = permH + (l >> 4) * 4;   // + 16*q per quad
    int rowoff = hh * 64 + (l & 3) * 16;   // byte offset within 256B row

    int start = row_start[d];
    int cnt = deg[d];
    float ad = adst[d * HEADS + hd];
    float e_self = lrelu(asrc[d * HEADS + hd] + ad);
    const char* hbbase = (const char*)hb;

    // self row load issued early
    uint4 us = *(const uint4*)(hbbase + (((uint32_t)d) << 8) + rowoff);

    float dsum = 0.f;
    v2f a0 = {0.f, 0.f}, a1 = {0.f, 0.f}, a2 = {0.f, 0.f}, a3 = {0.f, 0.f};
    const int* csr = csr_src + start;

#define ACC4(U, PJ)                         \
    {                                       \
        v2f p2 = {PJ, PJ};                  \
        a0 += p2 * up2((U).x);              \
        a1 += p2 * up2((U).y);              \
        a2 += p2 * up2((U).z);              \
        a3 += p2 * up2((U).w);              \
    }

    for (int j0 = 0; j0 < cnt; j0 += 32) {
        int ncnt = cnt - j0; if (ncnt > 32) ncnt = 32;
        // branchless clamped csr loads (dups hit L1)
        int jA = j0 + ci;      if (jA > cnt - 1) jA = cnt - 1;
        int jB = j0 + 16 + ci; if (jB > cnt - 1) jB = cnt - 1;
        int s0 = csr[jA];
        int s1 = csr[jB];

        // broadcast src ids; issue all 8 row loads back-to-back
        int sj0 = bperm_i(permb,      s0);
        int sj1 = bperm_i(permb + 16, s0);
        int sj2 = bperm_i(permb + 32, s0);
        int sj3 = bperm_i(permb + 48, s0);
        int sj4 = bperm_i(permb,      s1);
        int sj5 = bperm_i(permb + 16, s1);
        int sj6 = bperm_i(permb + 32, s1);
        int sj7 = bperm_i(permb + 48, s1);
        uint4 u0 = *(const uint4*)(hbbase + (((uint32_t)sj0) << 8) + rowoff);
        uint4 u1 = *(const uint4*)(hbbase + (((uint32_t)sj1) << 8) + rowoff);
        uint4 u2 = *(const uint4*)(hbbase + (((uint32_t)sj2) << 8) + rowoff);
        uint4 u3 = *(const uint4*)(hbbase + (((uint32_t)sj3) << 8) + rowoff);
        uint4 u4 = *(const uint4*)(hbbase + (((uint32_t)sj4) << 8) + rowoff);
        uint4 u5 = *(const uint4*)(hbbase + (((uint32_t)sj5) << 8) + rowoff);
        uint4 u6 = *(const uint4*)(hbbase + (((uint32_t)sj6) << 8) + rowoff);
        uint4 u7 = *(const uint4*)(hbbase + (((uint32_t)sj7) << 8) + rowoff);

        // alpha math overlaps the row loads
        float pe0 = (ci < ncnt)      ? __expf(lrelu(asrc[s0 * HEADS + hd] + ad)) : 0.f;
        float pe1 = (ci + 16 < ncnt) ? __expf(lrelu(asrc[s1 * HEADS + hd] + ad)) : 0.f;
        dsum += pe0 + pe1;
        float pj0 = bperm_f(permb,      pe0);
        float pj1 = bperm_f(permb + 16, pe0);
        float pj2 = bperm_f(permb + 32, pe0);
        float pj3 = bperm_f(permb + 48, pe0);
        float pj4 = bperm_f(permb,      pe1);
        float pj5 = bperm_f(permb + 16, pe1);
        float pj6 = bperm_f(permb + 32, pe1);
        float pj7 = bperm_f(permb + 48, pe1);

        ACC4(u0, pj0); ACC4(u1, pj1); ACC4(u2, pj2); ACC4(u3, pj3);
        ACC4(u4, pj4); ACC4(u5, pj5); ACC4(u6, pj6); ACC4(u7, pj7);
    }
#undef ACC4

    // denominator (edge layout, uniform per 16-lane head group)
    dsum += __shfl_xor(dsum, 8);
    dsum += __shfl_xor(dsum, 4);
    dsum += __shfl_xor(dsum, 2);
    dsum += __shfl_xor(dsum, 1);
    float ps = __expf(e_self);
    float inv = 1.f / (dsum + ps + 1e-16f);
    float psg = bperm_f(permH, ps);
    float invg = bperm_f(permH, inv);

    // reduce across the 4 edge-subgroups (lanes ^16, ^32)
    a0 += vshflxor(a0, 16); a0 += vshflxor(a0, 32);
    a1 += vshflxor(a1, 16); a1 += vshflxor(a1, 32);
    a2 += vshflxor(a2, 16); a2 += vshflxor(a2, 32);
    a3 += vshflxor(a3, 16); a3 += vshflxor(a3, 32);

    // self-loop contribution (once) + normalize
    v2f ps2 = {psg, psg};
    a0 += ps2 * up2(us.x);
    a1 += ps2 * up2(us.y);
    a2 += ps2 * up2(us.z);
    a3 += ps2 * up2(us.w);
    v2f iv2 = {invg, invg};
    a0 *= iv2; a1 *= iv2; a2 *= iv2; a3 *= iv2;

    // head mean (hh lives in bits 2,3 of l -> lanes ^4, ^8)
    a0 += vshflxor(a0, 4); a0 += vshflxor(a0, 8);
    a1 += vshflxor(a1, 4); a1 += vshflxor(a1, 8);
    a2 += vshflxor(a2, 4); a2 += vshflxor(a2, 8);
    a3 += vshflxor(a3, 4); a3 += vshflxor(a3, 8);

    if (l < 4) {   // lane kk=l writes channels 8l..8l+7
        const float4* bv = (const float4*)&bias[l * 8];
        float4 b0 = bv[0], b1 = bv[1];
        float4 o0, o1;
        o0.x = 0.25f * a0.x + b0.x; o0.y = 0.25f * a0.y + b0.y;
        o0.z = 0.25f * a1.x + b0.z; o0.w = 0.25f * a1.y + b0.w;
        o1.x = 0.25f * a2.x + b1.x; o1.y = 0.25f * a2.y + b1.y;
        o1.z = 0.25f * a3.x + b1.z; o1.w = 0.25f * a3.y + b1.w;
        o0.x = o0.x > 0.f ? o0.x : 0.f;  o0.y = o0.y > 0.f ? o0.y : 0.f;
        o0.z = o0.z > 0.f ? o0.z : 0.f;  o0.w = o0.w > 0.f ? o0.w : 0.f;
        o1.x = o1.x > 0.f ? o1.x : 0.f;  o1.y = o1.y > 0.f ? o1.y : 0.f;
        o1.z = o1.z > 0.f ? o1.z : 0.f;  o1.w = o1.w > 0.f ? o1.w : 0.f;
        float4* op = (float4*)&xout[(size_t)d * HID + l * 8];
        op[0] = o0;
        op[1] = o1;
    }
}

// ---------------- pooling + MLP ----------------

__global__ void pool_sum(const float* __restrict__ x, int n, float* __restrict__ g) {
    __shared__ float sm[256];
    int t = threadIdx.x;
    int c = t & 31;
    int r = t >> 5;   // 8 node-rows per block
    float acc = 0.f;
    for (int i = blockIdx.x * 8 + r; i < n; i += gridDim.x * 8)
        acc += x[(size_t)i * HID + c];
    sm[t] = acc;
    __syncthreads();
    if (t < 32) {
        float v = 0.f;
#pragma unroll
        for (int k = 0; k < 8; k++) v += sm[t + 32 * k];
        atomicAdd(&g[t], v);
    }
}

__global__ void mlp_final(const float* __restrict__ g,
                          const float* __restrict__ lw1, const float* __restrict__ lb1,
                          const float* __restrict__ lw2, const float* __restrict__ lb2,
                          float* __restrict__ out, float invn) {
    __shared__ float gm[32];
    int t = threadIdx.x;
    if (t < 32) gm[t] = g[t] * invn;
    __syncthreads();
    float q = 0.f;
    if (t < 16) {
        q = lb1[t];
        for (int c = 0; c < 32; c++) q += gm[c] * lw1[c * 16 + t];
        q = q > 0.f ? q : 0.f;
        q *= lw2[t];
    }
#pragma unroll
    for (int off = 8; off >= 1; off >>= 1) q += __shfl_xor(q, off);
    if (t == 0) out[0] = q + lb2[0];
}

// ---------------- launch ----------------

extern "C" void kernel_launch(void* const* d_in, const int* in_sizes, int n_in,
                              void* d_out, int out_size, void* d_ws, size_t ws_size,
                              hipStream_t stream) {
    const float* x   = (const float*)d_in[0];
    const int*   ei  = (const int*)d_in[1];
    const float* W1  = (const float*)d_in[2];
    const float* as1 = (const float*)d_in[3];
    const float* ad1 = (const float*)d_in[4];
    const float* b1  = (const float*)d_in[5];
    const float* W2  = (const float*)d_in[6];
    const float* as2 = (const float*)d_in[7];
    const float* ad2 = (const float*)d_in[8];
    const float* b2  = (const float*)d_in[9];
    const float* W3  = (const float*)d_in[10];
    const float* as3 = (const float*)d_in[11];
    const float* ad3 = (const float*)d_in[12];
    const float* b3  = (const float*)d_in[13];
    const float* lw1 = (const float*)d_in[14];
    const float* lb1 = (const float*)d_in[15];
    const float* lw2 = (const float*)d_in[16];
    const float* lb2 = (const float*)d_in[17];
    float* out = (float*)d_out;

    int n = in_sizes[0] / 128;   // 100000
    int E = in_sizes[1] / 2;     // 1600000
    int B = (n + 255) / 256;
    int nb = (n + 31) >> BSHIFT; // 3125 buckets

    // workspace carve (256B aligned)
    char* p = (char*)d_ws;
    auto alloc = [&](size_t bytes) -> void* {
        void* r = (void*)p;
        p += (bytes + 255) & ~(size_t)255;
        return r;
    };
    int* deg       = (int*)alloc((size_t)n * 4);
    int* row_start = (int*)alloc((size_t)n * 4);
    int* gcursor   = (int*)alloc((size_t)nb * 4);
    int* partial   = (int*)alloc((size_t)B * 4);
    int* csr       = (int*)alloc((size_t)E * 4);
    uint32_t* tmp  = (uint32_t*)alloc((size_t)E * 4);
    float* asrc    = (float*)alloc((size_t)n * HEADS * 4);
    float* adst    = (float*)alloc((size_t)n * HEADS * 4);
    uint32_t* hb   = (uint32_t*)alloc((size_t)n * 64 * 4);   // bf16x2 packed h (256B rows)
    float* xA      = (float*)alloc((size_t)n * HID * 4);
    float* xB      = (float*)alloc((size_t)n * HID * 4);
    float* g       = (float*)alloc(32 * 4);

    // CSR build (shared across all 3 layers)
    hipMemsetAsync(deg, 0, (size_t)n * 4, stream);
    deg_hist<<<(E + 255) / 256, 256, 0, stream>>>(ei, E, deg);
    scan_partial<<<B, 256, 0, stream>>>(deg, n, partial);
    scan_exclusive<<<1, 512, 0, stream>>>(partial, B);
    scan_final<<<B, 256, 0, stream>>>(deg, n, partial, row_start, gcursor);
    bucket_scatter<<<64, 512, 0, stream>>>(ei, E, nb, gcursor, tmp);
    bucket_sort<<<nb, 256, 0, stream>>>(tmp, row_start, n, E, csr);

    int gb = (n + 31) / 32;
    int ggb = (n + 3) / 4;

    // layer 1
    gemm_h<128><<<gb, 256, 0, stream>>>(x, W1, as1, ad1, hb, asrc, adst, n);
    aggregate<<<ggb, 256, 0, stream>>>(hb, asrc, adst, row_start, deg, csr, b1, xA, n);

    // layer 2
    gemm_h<32><<<gb, 256, 0, stream>>>(xA, W2, as2, ad2, hb, asrc, adst, n);
    aggregate<<<ggb, 256, 0, stream>>>(hb, asrc, adst, row_start, deg, csr, b2, xB, n);

    // layer 3
    gemm_h<32><<<gb, 256, 0, stream>>>(xB, W3, as3, ad3, hb, asrc, adst, n);
    aggregate<<<ggb, 256, 0, stream>>>(hb, asrc, adst, row_start, deg, csr, b3, xA, n);

    // pooling + MLP
    hipMemsetAsync(g, 0, 32 * 4, stream);
    pool_sum<<<256, 256, 0, stream>>>(xA, n, g);
    mlp_final<<<1, 64, 0, stream>>>(g, lw1, lb1, lw2, lb2, out, 1.0f / (float)n);
}

// Round 12
// 464.653 us; speedup vs baseline: 1.4910x; 1.2763x over previous
//
#include <hip/hip_runtime.h>
#include <hip/hip_bf16.h>

// GAT (3-layer, HEADS=4, HID=32, concat=False head-mean) + global mean pool + MLP.
// R12: gemms -> bf16 MFMA (16x16x32), transposed form C = Wbt x xs^T so packing
//     of bf16x2 h pairs is in-lane; alphas folded in as 8 extra W-columns (wasd)
//     forming a 9th MFMA tile whose rows 0-7 are asrc/adst (float4 stores).
//     Aggregate unchanged from R11 (row-gather wall ~19 G rows/s, 89 us/layer).

#define HEADS 4
#define HID 32
#define F_HID 128   // HEADS*HID
#define NEG_SLOPE 0.2f
#define BSHIFT 5
#define MAXB 3328   // max buckets supported (n <= 106496)

typedef float v2f __attribute__((ext_vector_type(2)));
using s8bf  = __attribute__((ext_vector_type(8))) short;   // 8 bf16 (4 VGPRs)
using f32x4 = __attribute__((ext_vector_type(4))) float;   // MFMA acc

__device__ __forceinline__ float lrelu(float v) { return v > 0.f ? v : NEG_SLOPE * v; }

__device__ __forceinline__ uint32_t bf16_rne(float f) {
    union { float f; uint32_t u; } c; c.f = f;
    return (c.u + 0x7fffu + ((c.u >> 16) & 1u)) >> 16;
}
__device__ __forceinline__ v2f up2(uint32_t u) {
    v2f r;
    r.x = __uint_as_float(u << 16);
    r.y = __uint_as_float(u & 0xffff0000u);
    return r;
}
__device__ __forceinline__ float bperm_f(int addr, float v) {
    return __int_as_float(__builtin_amdgcn_ds_bpermute(addr, __float_as_int(v)));
}
__device__ __forceinline__ int bperm_i(int addr, int v) {
    return __builtin_amdgcn_ds_bpermute(addr, v);
}
__device__ __forceinline__ v2f vshflxor(v2f v, int m) {
    v2f r; r.x = __shfl_xor(v.x, m); r.y = __shfl_xor(v.y, m); return r;
}

// ---------------- CSR build ----------------

__global__ void deg_hist(const int* __restrict__ ei, int E, int* __restrict__ deg) {
    int i = blockIdx.x * blockDim.x + threadIdx.x;
    if (i < E) {
        int d = ei[E + i];          // dst row of edge_index
        atomicAdd(&deg[d], 1);
    }
}

__global__ void scan_partial(const int* __restrict__ deg, int n, int* __restrict__ partial) {
    __shared__ int sm[256];
    int t = threadIdx.x;
    int i = blockIdx.x * 256 + t;
    sm[t] = (i < n) ? deg[i] : 0;
    __syncthreads();
    for (int s = 128; s > 0; s >>= 1) {
        if (t < s) sm[t] += sm[t + s];
        __syncthreads();
    }
    if (t == 0) partial[blockIdx.x] = sm[0];
}

__global__ __launch_bounds__(512) void scan_exclusive(int* partial, int B) {
    __shared__ int sm[512];
    int t = threadIdx.x;
    int carry = 0;
    for (int base = 0; base < B; base += 512) {
        int v = (base + t < B) ? partial[base + t] : 0;
        sm[t] = v;
        __syncthreads();
        for (int s = 1; s < 512; s <<= 1) {
            int add = (t >= s) ? sm[t - s] : 0;
            __syncthreads();
            sm[t] += add;
            __syncthreads();
        }
        if (base + t < B) partial[base + t] = carry + sm[t] - v;
        carry += sm[511];
        __syncthreads();
    }
}

__global__ void scan_final(const int* __restrict__ deg, int n, const int* __restrict__ partial,
                           int* __restrict__ row_start, int* __restrict__ gcursor) {
    __shared__ int sm[256];
    int t = threadIdx.x;
    int i = blockIdx.x * 256 + t;
    int v = (i < n) ? deg[i] : 0;
    sm[t] = v;
    __syncthreads();
    for (int s = 1; s < 256; s <<= 1) {
        int add = (t >= s) ? sm[t - s] : 0;
        __syncthreads();
        sm[t] += add;
        __syncthreads();
    }
    if (i < n) {
        int excl = partial[blockIdx.x] + sm[t] - v;
        row_start[i] = excl;
        if ((i & 31) == 0) gcursor[i >> BSHIFT] = excl;   // bucket cursor seed
    }
}

// Phase B: scatter edges into 32-node buckets; per-block contiguous runs.
__global__ __launch_bounds__(512) void bucket_scatter(const int* __restrict__ ei, int E, int nb,
                                                      int* __restrict__ gcursor,
                                                      uint32_t* __restrict__ tmp) {
    __shared__ int hist[MAXB];
    __shared__ int base[MAXB];
    int t = threadIdx.x;
    int per = (E + gridDim.x - 1) / gridDim.x;
    int e0 = blockIdx.x * per;
    int e1 = e0 + per; if (e1 > E) e1 = E;

    for (int i = t; i < nb; i += 512) hist[i] = 0;
    __syncthreads();
    for (int i = e0 + t; i < e1; i += 512) {
        int d = ei[E + i];
        atomicAdd(&hist[d >> BSHIFT], 1);
    }
    __syncthreads();
    for (int i = t; i < nb; i += 512) {
        int c = hist[i];
        base[i] = c ? atomicAdd(&gcursor[i], c) : 0;
        hist[i] = 0;   // reuse as local cursor
    }
    __syncthreads();
    for (int i = e0 + t; i < e1; i += 512) {
        int d = ei[E + i];
        int s = ei[i];
        int b = d >> BSHIFT;
        int loc = atomicAdd(&hist[b], 1);
        tmp[base[b] + loc] = ((uint32_t)s << BSHIFT) | (uint32_t)(d & 31);
    }
}

// Phase C: per-bucket exact placement (positions seeded from row_start — no recount).
__global__ __launch_bounds__(256) void bucket_sort(const uint32_t* __restrict__ tmp,
                                                   const int* __restrict__ row_start,
                                                   int n, int E,
                                                   int* __restrict__ csr) {
    __shared__ int cur[32];
    int b = blockIdx.x;
    int node0 = b << BSHIFT;
    int base = row_start[node0];
    int node1 = node0 + 32;
    int end = (node1 < n) ? row_start[node1] : E;
    int cnt = end - base;
    int t = threadIdx.x;
    if (t < 32) {
        int nd = node0 + t;
        cur[t] = (nd < n) ? (row_start[nd] - base) : 0;
    }
    __syncthreads();
    for (int i = t; i < cnt; i += 256) {
        uint32_t v = tmp[base + i];
        int pos = atomicAdd(&cur[v & 31], 1);
        csr[base + pos] = (int)(v >> BSHIFT);
    }
}

// ---------------- per-layer kernels ----------------

// prep: Wbt[r][k] bf16, padded stride LDK=FIN+8. Rows 0..127 = W^T (W col r);
// rows 128..135 = wasd columns (j<4: a_s head j; j>=4: a_d head j-4); rest 0.
template <int FIN>
__global__ void prep_w(const float* __restrict__ W, const float* __restrict__ a_s,
                       const float* __restrict__ a_d, unsigned short* __restrict__ wbt) {
    constexpr int LDK = FIN + 8;
    int t = blockIdx.x * 256 + threadIdx.x;
    if (t >= 144 * LDK) return;
    int r = t / LDK, k = t % LDK;
    float v = 0.f;
    if (k < FIN) {
        if (r < 128) {
            v = W[(size_t)k * F_HID + r];
        } else if (r < 136) {
            int j = r - 128;
            const float* av = (j < 4) ? a_s : a_d;
            int hd = j & 3;
            float s = 0.f;
            for (int c = 0; c < 32; c++)
                s += W[(size_t)k * F_HID + hd * 32 + c] * av[hd * 32 + c];
            v = s;
        }
    }
    wbt[t] = (unsigned short)bf16_rne(v);
}

// h = x @ W via bf16 MFMA, transposed: C = Wbt(16 wcols x 32k) * xs^T(32k x 16 nodes).
// Block: 4 waves, 32 nodes. Wave w: node-tile w>>1, col-tiles (w&1 ? 5..8 : 0..4).
// Tile 8 = wasd columns -> asrc/adst float4 stores. Tiles 0..7 -> hb bf16x2 pairs.
template <int FIN>
__global__ __launch_bounds__(256) void gemm_mfma(const float* __restrict__ x,
                                                 const unsigned short* __restrict__ wbt,
                                                 uint32_t* __restrict__ hb,
                                                 float* __restrict__ asrc,
                                                 float* __restrict__ adst, int n) {
    constexpr int LDK = FIN + 8;
    __shared__ unsigned short wl[144 * LDK];
    __shared__ unsigned short xs[32 * LDK];
    int t = threadIdx.x;
    int base = blockIdx.x * 32;

    {   // stage Wbt (bf16, already padded) via 16B copies
        const uint4* wg4 = (const uint4*)wbt;
        uint4* wl4 = (uint4*)wl;
        constexpr int W4 = 144 * LDK / 8;
        for (int i = t; i < W4; i += 256) wl4[i] = wg4[i];
    }
    {   // stage x tile -> bf16 LDS
        constexpr int XIT = 32 * FIN / 4;
        for (int idx = t; idx < XIT; idx += 256) {
            int node = idx / (FIN / 4);
            int k4 = (idx % (FIN / 4)) * 4;
            int gnode = base + node;
            float4 v;
            if (gnode < n) v = *(const float4*)&x[(size_t)gnode * FIN + k4];
            else { v.x = 0.f; v.y = 0.f; v.z = 0.f; v.w = 0.f; }
            unsigned short* dst = &xs[node * LDK + k4];
            dst[0] = (unsigned short)bf16_rne(v.x);
            dst[1] = (unsigned short)bf16_rne(v.y);
            dst[2] = (unsigned short)bf16_rne(v.z);
            dst[3] = (unsigned short)bf16_rne(v.w);
        }
    }
    __syncthreads();

    int w = t >> 6;
    int l = t & 63;
    int nt = w >> 1;                 // node tile 0/1
    int ct0 = (w & 1) ? 5 : 0;
    int ct1 = (w & 1) ? 9 : 5;
    int lr = l & 15, lg = l >> 4;
    int node = base + nt * 16 + lr;
    const unsigned short* xrow = &xs[(nt * 16 + lr) * LDK + lg * 8];

    for (int ct = ct0; ct < ct1; ct++) {
        f32x4 acc = {0.f, 0.f, 0.f, 0.f};
        const unsigned short* arow = &wl[(ct * 16 + lr) * LDK + lg * 8];
#pragma unroll
        for (int kt = 0; kt < FIN / 32; kt++) {
            s8bf a = *(const s8bf*)(arow + kt * 32);
            s8bf b = *(const s8bf*)(xrow + kt * 32);
            acc = __builtin_amdgcn_mfma_f32_16x16x32_bf16(a, b, acc, 0, 0, 0);
        }
        if (node < n) {
            if (ct < 8) {
                // lane holds wcols 16ct+4lg .. +3 for this node -> 2 bf16x2 pairs
                uint2 pp;
                pp.x = bf16_rne(acc[0]) | (bf16_rne(acc[1]) << 16);
                pp.y = bf16_rne(acc[2]) | (bf16_rne(acc[3]) << 16);
                *(uint2*)&hb[(size_t)node * 64 + ct * 8 + lg * 2] = pp;
            } else {
                // tile 8: rows 0-3 = asrc heads, rows 4-7 = adst heads
                float4 o; o.x = acc[0]; o.y = acc[1]; o.z = acc[2]; o.w = acc[3];
                if (lg == 0)      *(float4*)&asrc[node * 4] = o;
                else if (lg == 1) *(float4*)&adst[node * 4] = o;
            }
        }
    }
}

// Wave-per-node aggregate over bf16x2 h (256B rows), no online max. (R11, unchanged)
__global__ __launch_bounds__(256) void aggregate(const uint32_t* __restrict__ hb,
                                                 const float* __restrict__ asrc,
                                                 const float* __restrict__ adst,
                                                 const int* __restrict__ row_start,
                                                 const int* __restrict__ deg,
                                                 const int* __restrict__ csr_src,
                                                 const float* __restrict__ bias,
                                                 float* __restrict__ xout, int n) {
    int d = blockIdx.x * 4 + (threadIdx.x >> 6);
    if (d >= n) return;
    int l = threadIdx.x & 63;
    int hd = l >> 4;                 // edge-phase head
    int ci = l & 15;                 // edge-phase edge slot
    int hh = (l & 15) >> 2;          // gather-phase head
    int permH = hh << 6;
    int permb = permH + (l >> 4) * 4;
    int rowoff = hh * 64 + (l & 3) * 16;

    int start = row_start[d];
    int cnt = deg[d];
    float ad = adst[d * HEADS + hd];
    float e_self = lrelu(asrc[d * HEADS + hd] + ad);
    const char* hbbase = (const char*)hb;

    uint4 us = *(const uint4*)(hbbase + (((uint32_t)d) << 8) + rowoff);

    float dsum = 0.f;
    v2f a0 = {0.f, 0.f}, a1 = {0.f, 0.f}, a2 = {0.f, 0.f}, a3 = {0.f, 0.f};
    const int* csr = csr_src + start;

#define ACC4(U, PJ)                         \
    {                                       \
        v2f p2 = {PJ, PJ};                  \
        a0 += p2 * up2((U).x);              \
        a1 += p2 * up2((U).y);              \
        a2 += p2 * up2((U).z);              \
        a3 += p2 * up2((U).w);              \
    }

    for (int j0 = 0; j0 < cnt; j0 += 32) {
        int ncnt = cnt - j0; if (ncnt > 32) ncnt = 32;
        int jA = j0 + ci;      if (jA > cnt - 1) jA = cnt - 1;
        int jB = j0 + 16 + ci; if (jB > cnt - 1) jB = cnt - 1;
        int s0 = csr[jA];
        int s1 = csr[jB];

        int sj0 = bperm_i(permb,      s0);
        int sj1 = bperm_i(permb + 16, s0);
        int sj2 = bperm_i(permb + 32, s0);
        int sj3 = bperm_i(permb + 48, s0);
        int sj4 = bperm_i(permb,      s1);
        int sj5 = bperm_i(permb + 16, s1);
        int sj6 = bperm_i(permb + 32, s1);
        int sj7 = bperm_i(permb + 48, s1);
        uint4 u0 = *(const uint4*)(hbbase + (((uint32_t)sj0) << 8) + rowoff);
        uint4 u1 = *(const uint4*)(hbbase + (((uint32_t)sj1) << 8) + rowoff);
        uint4 u2 = *(const uint4*)(hbbase + (((uint32_t)sj2) << 8) + rowoff);
        uint4 u3 = *(const uint4*)(hbbase + (((uint32_t)sj3) << 8) + rowoff);
        uint4 u4 = *(const uint4*)(hbbase + (((uint32_t)sj4) << 8) + rowoff);
        uint4 u5 = *(const uint4*)(hbbase + (((uint32_t)sj5) << 8) + rowoff);
        uint4 u6 = *(const uint4*)(hbbase + (((uint32_t)sj6) << 8) + rowoff);
        uint4 u7 = *(const uint4*)(hbbase + (((uint32_t)sj7) << 8) + rowoff);

        float pe0 = (ci < ncnt)      ? __expf(lrelu(asrc[s0 * HEADS + hd] + ad)) : 0.f;
        float pe1 = (ci + 16 < ncnt) ? __expf(lrelu(asrc[s1 * HEADS + hd] + ad)) : 0.f;
        dsum += pe0 + pe1;
        float pj0 = bperm_f(permb,      pe0);
        float pj1 = bperm_f(permb + 16, pe0);
        float pj2 = bperm_f(permb + 32, pe0);
        float pj3 = bperm_f(permb + 48, pe0);
        float pj4 = bperm_f(permb,      pe1);
        float pj5 = bperm_f(permb + 16, pe1);
        float pj6 = bperm_f(permb + 32, pe1);
        float pj7 = bperm_f(permb + 48, pe1);

        ACC4(u0, pj0); ACC4(u1, pj1); ACC4(u2, pj2); ACC4(u3, pj3);
        ACC4(u4, pj4); ACC4(u5, pj5); ACC4(u6, pj6); ACC4(u7, pj7);
    }
#undef ACC4

    dsum += __shfl_xor(dsum, 8);
    dsum += __shfl_xor(dsum, 4);
    dsum += __shfl_xor(dsum, 2);
    dsum += __shfl_xor(dsum, 1);
    float ps = __expf(e_self);
    float inv = 1.f / (dsum + ps + 1e-16f);
    float psg = bperm_f(permH, ps);
    float invg = bperm_f(permH, inv);

    a0 += vshflxor(a0, 16); a0 += vshflxor(a0, 32);
    a1 += vshflxor(a1, 16); a1 += vshflxor(a1, 32);
    a2 += vshflxor(a2, 16); a2 += vshflxor(a2, 32);
    a3 += vshflxor(a3, 16); a3 += vshflxor(a3, 32);

    v2f ps2 = {psg, psg};
    a0 += ps2 * up2(us.x);
    a1 += ps2 * up2(us.y);
    a2 += ps2 * up2(us.z);
    a3 += ps2 * up2(us.w);
    v2f iv2 = {invg, invg};
    a0 *= iv2; a1 *= iv2; a2 *= iv2; a3 *= iv2;

    a0 += vshflxor(a0, 4); a0 += vshflxor(a0, 8);
    a1 += vshflxor(a1, 4); a1 += vshflxor(a1, 8);
    a2 += vshflxor(a2, 4); a2 += vshflxor(a2, 8);
    a3 += vshflxor(a3, 4); a3 += vshflxor(a3, 8);

    if (l < 4) {
        const float4* bv = (const float4*)&bias[l * 8];
        float4 b0 = bv[0], b1 = bv[1];
        float4 o0, o1;
        o0.x = 0.25f * a0.x + b0.x; o0.y = 0.25f * a0.y + b0.y;
        o0.z = 0.25f * a1.x + b0.z; o0.w = 0.25f * a1.y + b0.w;
        o1.x = 0.25f * a2.x + b1.x; o1.y = 0.25f * a2.y + b1.y;
        o1.z = 0.25f * a3.x + b1.z; o1.w = 0.25f * a3.y + b1.w;
        o0.x = o0.x > 0.f ? o0.x : 0.f;  o0.y = o0.y > 0.f ? o0.y : 0.f;
        o0.z = o0.z > 0.f ? o0.z : 0.f;  o0.w = o0.w > 0.f ? o0.w : 0.f;
        o1.x = o1.x > 0.f ? o1.x : 0.f;  o1.y = o1.y > 0.f ? o1.y : 0.f;
        o1.z = o1.z > 0.f ? o1.z : 0.f;  o1.w = o1.w > 0.f ? o1.w : 0.f;
        float4* op = (float4*)&xout[(size_t)d * HID + l * 8];
        op[0] = o0;
        op[1] = o1;
    }
}

// ---------------- pooling + MLP ----------------

__global__ void pool_sum(const float* __restrict__ x, int n, float* __restrict__ g) {
    __shared__ float sm[256];
    int t = threadIdx.x;
    int c = t & 31;
    int r = t >> 5;   // 8 node-rows per block
    float acc = 0.f;
    for (int i = blockIdx.x * 8 + r; i < n; i += gridDim.x * 8)
        acc += x[(size_t)i * HID + c];
    sm[t] = acc;
    __syncthreads();
    if (t < 32) {
        float v = 0.f;
#pragma unroll
        for (int k = 0; k < 8; k++) v += sm[t + 32 * k];
        atomicAdd(&g[t], v);
    }
}

__global__ void mlp_final(const float* __restrict__ g,
                          const float* __restrict__ lw1, const float* __restrict__ lb1,
                          const float* __restrict__ lw2, const float* __restrict__ lb2,
                          float* __restrict__ out, float invn) {
    __shared__ float gm[32];
    int t = threadIdx.x;
    if (t < 32) gm[t] = g[t] * invn;
    __syncthreads();
    float q = 0.f;
    if (t < 16) {
        q = lb1[t];
        for (int c = 0; c < 32; c++) q += gm[c] * lw1[c * 16 + t];
        q = q > 0.f ? q : 0.f;
        q *= lw2[t];
    }
#pragma unroll
    for (int off = 8; off >= 1; off >>= 1) q += __shfl_xor(q, off);
    if (t == 0) out[0] = q + lb2[0];
}

// ---------------- launch ----------------

extern "C" void kernel_launch(void* const* d_in, const int* in_sizes, int n_in,
                              void* d_out, int out_size, void* d_ws, size_t ws_size,
                              hipStream_t stream) {
    const float* x   = (const float*)d_in[0];
    const int*   ei  = (const int*)d_in[1];
    const float* W1  = (const float*)d_in[2];
    const float* as1 = (const float*)d_in[3];
    const float* ad1 = (const float*)d_in[4];
    const float* b1  = (const float*)d_in[5];
    const float* W2  = (const float*)d_in[6];
    const float* as2 = (const float*)d_in[7];
    const float* ad2 = (const float*)d_in[8];
    const float* b2  = (const float*)d_in[9];
    const float* W3  = (const float*)d_in[10];
    const float* as3 = (const float*)d_in[11];
    const float* ad3 = (const float*)d_in[12];
    const float* b3  = (const float*)d_in[13];
    const float* lw1 = (const float*)d_in[14];
    const float* lb1 = (const float*)d_in[15];
    const float* lw2 = (const float*)d_in[16];
    const float* lb2 = (const float*)d_in[17];
    float* out = (float*)d_out;

    int n = in_sizes[0] / 128;   // 100000
    int E = in_sizes[1] / 2;     // 1600000
    int B = (n + 255) / 256;
    int nb = (n + 31) >> BSHIFT; // 3125 buckets

    // workspace carve (256B aligned)
    char* p = (char*)d_ws;
    auto alloc = [&](size_t bytes) -> void* {
        void* r = (void*)p;
        p += (bytes + 255) & ~(size_t)255;
        return r;
    };
    int* deg       = (int*)alloc((size_t)n * 4);
    int* row_start = (int*)alloc((size_t)n * 4);
    int* gcursor   = (int*)alloc((size_t)nb * 4);
    int* partial   = (int*)alloc((size_t)B * 4);
    int* csr       = (int*)alloc((size_t)E * 4);
    uint32_t* tmp  = (uint32_t*)alloc((size_t)E * 4);
    float* asrc    = (float*)alloc((size_t)n * HEADS * 4);
    float* adst    = (float*)alloc((size_t)n * HEADS * 4);
    uint32_t* hb   = (uint32_t*)alloc((size_t)n * 64 * 4);   // bf16x2 packed h (256B rows)
    float* xA      = (float*)alloc((size_t)n * HID * 4);
    float* xB      = (float*)alloc((size_t)n * HID * 4);
    float* g       = (float*)alloc(32 * 4);
    unsigned short* wbt = (unsigned short*)alloc((size_t)144 * 136 * 2);  // padded bf16 W^T (+wasd)

    // CSR build (shared across all 3 layers)
    hipMemsetAsync(deg, 0, (size_t)n * 4, stream);
    deg_hist<<<(E + 255) / 256, 256, 0, stream>>>(ei, E, deg);
    scan_partial<<<B, 256, 0, stream>>>(deg, n, partial);
    scan_exclusive<<<1, 512, 0, stream>>>(partial, B);
    scan_final<<<B, 256, 0, stream>>>(deg, n, partial, row_start, gcursor);
    bucket_scatter<<<64, 512, 0, stream>>>(ei, E, nb, gcursor, tmp);
    bucket_sort<<<nb, 256, 0, stream>>>(tmp, row_start, n, E, csr);

    int gb = (n + 31) / 32;
    int ggb = (n + 3) / 4;
    int wg128 = (144 * 136 + 255) / 256;
    int wg32  = (144 * 40 + 255) / 256;

    // layer 1
    prep_w<128><<<wg128, 256, 0, stream>>>(W1, as1, ad1, wbt);
    gemm_mfma<128><<<gb, 256, 0, stream>>>(x, wbt, hb, asrc, adst, n);
    aggregate<<<ggb, 256, 0, stream>>>(hb, asrc, adst, row_start, deg, csr, b1, xA, n);

    // layer 2
    prep_w<32><<<wg32, 256, 0, stream>>>(W2, as2, ad2, wbt);
    gemm_mfma<32><<<gb, 256, 0, stream>>>(xA, wbt, hb, asrc, adst, n);
    aggregate<<<ggb, 256, 0, stream>>>(hb, asrc, adst, row_start, deg, csr, b2, xB, n);

    // layer 3
    prep_w<32><<<wg32, 256, 0, stream>>>(W3, as3, ad3, wbt);
    gemm_mfma<32><<<gb, 256, 0, stream>>>(xB, wbt, hb, asrc, adst, n);
    aggregate<<<ggb, 256, 0, stream>>>(hb, asrc, adst, row_start, deg, csr, b3, xA, n);

    // pooling + MLP
    hipMemsetAsync(g, 0, 32 * 4, stream);
    pool_sum<<<256, 256, 0, stream>>>(xA, n, g);
    mlp_final<<<1, 64, 0, stream>>>(g, lw1, lb1, lw2, lb2, out, 1.0f / (float)n);
}

// Round 13
// 403.822 us; speedup vs baseline: 1.7156x; 1.1506x over previous
//
#include <hip/hip_runtime.h>
#include <hip/hip_bf16.h>

// GAT (3-layer, HEADS=4, HID=32, concat=False head-mean) + global mean pool + MLP.
// R13: CSR build reworked at bucket granularity: bucket_hist(256 blk, LDS) +
//     bucket_scan(3125+1) + bucket_scatter(256 blk, was 64) + bucket_sort that
//     derives row_start/deg locally. Node-level hist+3-scan pipeline removed.
//     gemm_mfma: 64 nodes/block (W-staging amortized 2x).
//     Aggregate unchanged (R11 structure; ~19 G rows/s random-gather wall).

#define HEADS 4
#define HID 32
#define F_HID 128   // HEADS*HID
#define NEG_SLOPE 0.2f
#define BSHIFT 5
#define MAXB 3328   // max buckets supported (n <= 106496)

typedef float v2f __attribute__((ext_vector_type(2)));
using s8bf  = __attribute__((ext_vector_type(8))) short;   // 8 bf16 (4 VGPRs)
using f32x4 = __attribute__((ext_vector_type(4))) float;   // MFMA acc

__device__ __forceinline__ float lrelu(float v) { return v > 0.f ? v : NEG_SLOPE * v; }

__device__ __forceinline__ uint32_t bf16_rne(float f) {
    union { float f; uint32_t u; } c; c.f = f;
    return (c.u + 0x7fffu + ((c.u >> 16) & 1u)) >> 16;
}
__device__ __forceinline__ v2f up2(uint32_t u) {
    v2f r;
    r.x = __uint_as_float(u << 16);
    r.y = __uint_as_float(u & 0xffff0000u);
    return r;
}
__device__ __forceinline__ float bperm_f(int addr, float v) {
    return __int_as_float(__builtin_amdgcn_ds_bpermute(addr, __float_as_int(v)));
}
__device__ __forceinline__ int bperm_i(int addr, int v) {
    return __builtin_amdgcn_ds_bpermute(addr, v);
}
__device__ __forceinline__ v2f vshflxor(v2f v, int m) {
    v2f r; r.x = __shfl_xor(v.x, m); r.y = __shfl_xor(v.y, m); return r;
}

// ---------------- CSR build (bucket-granular) ----------------

// per-block LDS histogram over buckets, merged into global bcnt
__global__ __launch_bounds__(256) void bucket_hist(const int* __restrict__ ei, int E, int nb,
                                                   int* __restrict__ bcnt) {
    __shared__ int h[MAXB];
    int t = threadIdx.x;
    for (int i = t; i < nb; i += 256) h[i] = 0;
    __syncthreads();
    int per = (E + gridDim.x - 1) / gridDim.x;
    int e0 = blockIdx.x * per;
    int e1 = e0 + per; if (e1 > E) e1 = E;
    for (int i = e0 + t; i < e1; i += 256)
        atomicAdd(&h[ei[E + i] >> BSHIFT], 1);
    __syncthreads();
    for (int i = t; i < nb; i += 256)
        if (h[i]) atomicAdd(&bcnt[i], h[i]);
}

// single-block exclusive scan over nb bucket counts; gbase[nb] = E total.
__global__ __launch_bounds__(512) void bucket_scan(const int* __restrict__ bcnt, int nb,
                                                   int* __restrict__ gbase,
                                                   int* __restrict__ gcursor) {
    __shared__ int sm[512];
    int t = threadIdx.x;
    int carry = 0;
    for (int b0 = 0; b0 < nb; b0 += 512) {
        int v = (b0 + t < nb) ? bcnt[b0 + t] : 0;
        sm[t] = v;
        __syncthreads();
        for (int s = 1; s < 512; s <<= 1) {
            int add = (t >= s) ? sm[t - s] : 0;
            __syncthreads();
            sm[t] += add;
            __syncthreads();
        }
        if (b0 + t < nb) {
            int ex = carry + sm[t] - v;
            gbase[b0 + t] = ex;
            gcursor[b0 + t] = ex;
        }
        carry += sm[511];
        __syncthreads();
    }
    if (t == 0) gbase[nb] = carry;
}

// scatter edges into 32-node buckets; per-block contiguous runs.
__global__ __launch_bounds__(512) void bucket_scatter(const int* __restrict__ ei, int E, int nb,
                                                      int* __restrict__ gcursor,
                                                      uint32_t* __restrict__ tmp) {
    __shared__ int hist[MAXB];
    __shared__ int base[MAXB];
    int t = threadIdx.x;
    int per = (E + gridDim.x - 1) / gridDim.x;
    int e0 = blockIdx.x * per;
    int e1 = e0 + per; if (e1 > E) e1 = E;

    for (int i = t; i < nb; i += 512) hist[i] = 0;
    __syncthreads();
    for (int i = e0 + t; i < e1; i += 512) {
        int d = ei[E + i];
        atomicAdd(&hist[d >> BSHIFT], 1);
    }
    __syncthreads();
    for (int i = t; i < nb; i += 512) {
        int c = hist[i];
        base[i] = c ? atomicAdd(&gcursor[i], c) : 0;
        hist[i] = 0;   // reuse as local cursor
    }
    __syncthreads();
    for (int i = e0 + t; i < e1; i += 512) {
        int d = ei[E + i];
        int s = ei[i];
        int b = d >> BSHIFT;
        int loc = atomicAdd(&hist[b], 1);
        tmp[base[b] + loc] = ((uint32_t)s << BSHIFT) | (uint32_t)(d & 31);
    }
}

// per-bucket: derive per-node deg/row_start locally, then exact placement.
__global__ __launch_bounds__(256) void bucket_sort(const uint32_t* __restrict__ tmp,
                                                   const int* __restrict__ gbase,
                                                   int n, int* __restrict__ csr,
                                                   int* __restrict__ row_start,
                                                   int* __restrict__ deg) {
    __shared__ int cnt[32], pre[32];
    int b = blockIdx.x;
    int node0 = b << BSHIFT;
    int base = gbase[b];
    int cntE = gbase[b + 1] - base;
    int t = threadIdx.x;
    if (t < 32) cnt[t] = 0;
    __syncthreads();
    for (int i = t; i < cntE; i += 256)
        atomicAdd(&cnt[tmp[base + i] & 31], 1);
    __syncthreads();
    if (t == 0) {
        int run = 0;
        for (int i = 0; i < 32; i++) { pre[i] = run; run += cnt[i]; }
    }
    __syncthreads();
    if (t < 32) {
        int nd = node0 + t;
        if (nd < n) {
            row_start[nd] = base + pre[t];
            deg[nd] = cnt[t];
        }
        cnt[t] = pre[t];   // reuse as cursor
    }
    __syncthreads();
    for (int i = t; i < cntE; i += 256) {
        uint32_t v = tmp[base + i];
        int pos = atomicAdd(&cnt[v & 31], 1);
        csr[base + pos] = (int)(v >> BSHIFT);
    }
}

// ---------------- per-layer kernels ----------------

// prep: Wbt[r][k] bf16, padded stride LDK=FIN+8. Rows 0..127 = W^T (W col r);
// rows 128..135 = wasd columns (j<4: a_s head j; j>=4: a_d head j-4); rest 0.
template <int FIN>
__global__ void prep_w(const float* __restrict__ W, const float* __restrict__ a_s,
                       const float* __restrict__ a_d, unsigned short* __restrict__ wbt) {
    constexpr int LDK = FIN + 8;
    int t = blockIdx.x * 256 + threadIdx.x;
    if (t >= 144 * LDK) return;
    int r = t / LDK, k = t % LDK;
    float v = 0.f;
    if (k < FIN) {
        if (r < 128) {
            v = W[(size_t)k * F_HID + r];
        } else if (r < 136) {
            int j = r - 128;
            const float* av = (j < 4) ? a_s : a_d;
            int hd = j & 3;
            float s = 0.f;
            for (int c = 0; c < 32; c++)
                s += W[(size_t)k * F_HID + hd * 32 + c] * av[hd * 32 + c];
            v = s;
        }
    }
    wbt[t] = (unsigned short)bf16_rne(v);
}

// h = x @ W via bf16 MFMA, transposed: C = Wbt(16 wcols x 32k) * xs^T(32k x 16 nodes).
// 64 nodes/block, 4 waves: wave w = node-tile w, all 9 col-tiles.
// Tile 8 = wasd columns -> asrc/adst float4 stores. Tiles 0..7 -> hb bf16x2 pairs.
template <int FIN>
__global__ __launch_bounds__(256) void gemm_mfma(const float* __restrict__ x,
                                                 const unsigned short* __restrict__ wbt,
                                                 uint32_t* __restrict__ hb,
                                                 float* __restrict__ asrc,
                                                 float* __restrict__ adst, int n) {
    constexpr int LDK = FIN + 8;
    constexpr int NPB = 64;
    __shared__ unsigned short wl[144 * LDK];
    __shared__ unsigned short xs[NPB * LDK];
    int t = threadIdx.x;
    int base = blockIdx.x * NPB;

    {   // stage Wbt (bf16, already padded) via 16B copies
        const uint4* wg4 = (const uint4*)wbt;
        uint4* wl4 = (uint4*)wl;
        constexpr int W4 = 144 * LDK / 8;
        for (int i = t; i < W4; i += 256) wl4[i] = wg4[i];
    }
    {   // stage x tile -> bf16 LDS
        constexpr int XIT = NPB * FIN / 4;
        for (int idx = t; idx < XIT; idx += 256) {
            int node = idx / (FIN / 4);
            int k4 = (idx % (FIN / 4)) * 4;
            int gnode = base + node;
            float4 v;
            if (gnode < n) v = *(const float4*)&x[(size_t)gnode * FIN + k4];
            else { v.x = 0.f; v.y = 0.f; v.z = 0.f; v.w = 0.f; }
            unsigned short* dst = &xs[node * LDK + k4];
            dst[0] = (unsigned short)bf16_rne(v.x);
            dst[1] = (unsigned short)bf16_rne(v.y);
            dst[2] = (unsigned short)bf16_rne(v.z);
            dst[3] = (unsigned short)bf16_rne(v.w);
        }
    }
    __syncthreads();

    int w = t >> 6;
    int l = t & 63;
    int lr = l & 15, lg = l >> 4;
    int node = base + w * 16 + lr;
    const unsigned short* xrow = &xs[(w * 16 + lr) * LDK + lg * 8];

    for (int ct = 0; ct < 9; ct++) {
        f32x4 acc = {0.f, 0.f, 0.f, 0.f};
        const unsigned short* arow = &wl[(ct * 16 + lr) * LDK + lg * 8];
#pragma unroll
        for (int kt = 0; kt < FIN / 32; kt++) {
            s8bf a = *(const s8bf*)(arow + kt * 32);
            s8bf b = *(const s8bf*)(xrow + kt * 32);
            acc = __builtin_amdgcn_mfma_f32_16x16x32_bf16(a, b, acc, 0, 0, 0);
        }
        if (node < n) {
            if (ct < 8) {
                uint2 pp;
                pp.x = bf16_rne(acc[0]) | (bf16_rne(acc[1]) << 16);
                pp.y = bf16_rne(acc[2]) | (bf16_rne(acc[3]) << 16);
                *(uint2*)&hb[(size_t)node * 64 + ct * 8 + lg * 2] = pp;
            } else {
                float4 o; o.x = acc[0]; o.y = acc[1]; o.z = acc[2]; o.w = acc[3];
                if (lg == 0)      *(float4*)&asrc[node * 4] = o;
                else if (lg == 1) *(float4*)&adst[node * 4] = o;
            }
        }
    }
}

// Wave-per-node aggregate over bf16x2 h (256B rows), no online max. (R11, unchanged)
__global__ __launch_bounds__(256) void aggregate(const uint32_t* __restrict__ hb,
                                                 const float* __restrict__ asrc,
                                                 const float* __restrict__ adst,
                                                 const int* __restrict__ row_start,
                                                 const int* __restrict__ deg,
                                                 const int* __restrict__ csr_src,
                                                 const float* __restrict__ bias,
                                                 float* __restrict__ xout, int n) {
    int d = blockIdx.x * 4 + (threadIdx.x >> 6);
    if (d >= n) return;
    int l = threadIdx.x & 63;
    int hd = l >> 4;                 // edge-phase head
    int ci = l & 15;                 // edge-phase edge slot
    int hh = (l & 15) >> 2;          // gather-phase head
    int permH = hh << 6;
    int permb = permH + (l >> 4) * 4;
    int rowoff = hh * 64 + (l & 3) * 16;

    int start = row_start[d];
    int cnt = deg[d];
    float ad = adst[d * HEADS + hd];
    float e_self = lrelu(asrc[d * HEADS + hd] + ad);
    const char* hbbase = (const char*)hb;

    uint4 us = *(const uint4*)(hbbase + (((uint32_t)d) << 8) + rowoff);

    float dsum = 0.f;
    v2f a0 = {0.f, 0.f}, a1 = {0.f, 0.f}, a2 = {0.f, 0.f}, a3 = {0.f, 0.f};
    const int* csr = csr_src + start;

#define ACC4(U, PJ)                         \
    {                                       \
        v2f p2 = {PJ, PJ};                  \
        a0 += p2 * up2((U).x);              \
        a1 += p2 * up2((U).y);              \
        a2 += p2 * up2((U).z);              \
        a3 += p2 * up2((U).w);              \
    }

    for (int j0 = 0; j0 < cnt; j0 += 32) {
        int ncnt = cnt - j0; if (ncnt > 32) ncnt = 32;
        int jA = j0 + ci;      if (jA > cnt - 1) jA = cnt - 1;
        int jB = j0 + 16 + ci; if (jB > cnt - 1) jB = cnt - 1;
        int s0 = csr[jA];
        int s1 = csr[jB];

        int sj0 = bperm_i(permb,      s0);
        int sj1 = bperm_i(permb + 16, s0);
        int sj2 = bperm_i(permb + 32, s0);
        int sj3 = bperm_i(permb + 48, s0);
        int sj4 = bperm_i(permb,      s1);
        int sj5 = bperm_i(permb + 16, s1);
        int sj6 = bperm_i(permb + 32, s1);
        int sj7 = bperm_i(permb + 48, s1);
        uint4 u0 = *(const uint4*)(hbbase + (((uint32_t)sj0) << 8) + rowoff);
        uint4 u1 = *(const uint4*)(hbbase + (((uint32_t)sj1) << 8) + rowoff);
        uint4 u2 = *(const uint4*)(hbbase + (((uint32_t)sj2) << 8) + rowoff);
        uint4 u3 = *(const uint4*)(hbbase + (((uint32_t)sj3) << 8) + rowoff);
        uint4 u4 = *(const uint4*)(hbbase + (((uint32_t)sj4) << 8) + rowoff);
        uint4 u5 = *(const uint4*)(hbbase + (((uint32_t)sj5) << 8) + rowoff);
        uint4 u6 = *(const uint4*)(hbbase + (((uint32_t)sj6) << 8) + rowoff);
        uint4 u7 = *(const uint4*)(hbbase + (((uint32_t)sj7) << 8) + rowoff);

        float pe0 = (ci < ncnt)      ? __expf(lrelu(asrc[s0 * HEADS + hd] + ad)) : 0.f;
        float pe1 = (ci + 16 < ncnt) ? __expf(lrelu(asrc[s1 * HEADS + hd] + ad)) : 0.f;
        dsum += pe0 + pe1;
        float pj0 = bperm_f(permb,      pe0);
        float pj1 = bperm_f(permb + 16, pe0);
        float pj2 = bperm_f(permb + 32, pe0);
        float pj3 = bperm_f(permb + 48, pe0);
        float pj4 = bperm_f(permb,      pe1);
        float pj5 = bperm_f(permb + 16, pe1);
        float pj6 = bperm_f(permb + 32, pe1);
        float pj7 = bperm_f(permb + 48, pe1);

        ACC4(u0, pj0); ACC4(u1, pj1); ACC4(u2, pj2); ACC4(u3, pj3);
        ACC4(u4, pj4); ACC4(u5, pj5); ACC4(u6, pj6); ACC4(u7, pj7);
    }
#undef ACC4

    dsum += __shfl_xor(dsum, 8);
    dsum += __shfl_xor(dsum, 4);
    dsum += __shfl_xor(dsum, 2);
    dsum += __shfl_xor(dsum, 1);
    float ps = __expf(e_self);
    float inv = 1.f / (dsum + ps + 1e-16f);
    float psg = bperm_f(permH, ps);
    float invg = bperm_f(permH, inv);

    a0 += vshflxor(a0, 16); a0 += vshflxor(a0, 32);
    a1 += vshflxor(a1, 16); a1 += vshflxor(a1, 32);
    a2 += vshflxor(a2, 16); a2 += vshflxor(a2, 32);
    a3 += vshflxor(a3, 16); a3 += vshflxor(a3, 32);

    v2f ps2 = {psg, psg};
    a0 += ps2 * up2(us.x);
    a1 += ps2 * up2(us.y);
    a2 += ps2 * up2(us.z);
    a3 += ps2 * up2(us.w);
    v2f iv2 = {invg, invg};
    a0 *= iv2; a1 *= iv2; a2 *= iv2; a3 *= iv2;

    a0 += vshflxor(a0, 4); a0 += vshflxor(a0, 8);
    a1 += vshflxor(a1, 4); a1 += vshflxor(a1, 8);
    a2 += vshflxor(a2, 4); a2 += vshflxor(a2, 8);
    a3 += vshflxor(a3, 4); a3 += vshflxor(a3, 8);

    if (l < 4) {
        const float4* bv = (const float4*)&bias[l * 8];
        float4 b0 = bv[0], b1 = bv[1];
        float4 o0, o1;
        o0.x = 0.25f * a0.x + b0.x; o0.y = 0.25f * a0.y + b0.y;
        o0.z = 0.25f * a1.x + b0.z; o0.w = 0.25f * a1.y + b0.w;
        o1.x = 0.25f * a2.x + b1.x; o1.y = 0.25f * a2.y + b1.y;
        o1.z = 0.25f * a3.x + b1.z; o1.w = 0.25f * a3.y + b1.w;
        o0.x = o0.x > 0.f ? o0.x : 0.f;  o0.y = o0.y > 0.f ? o0.y : 0.f;
        o0.z = o0.z > 0.f ? o0.z : 0.f;  o0.w = o0.w > 0.f ? o0.w : 0.f;
        o1.x = o1.x > 0.f ? o1.x : 0.f;  o1.y = o1.y > 0.f ? o1.y : 0.f;
        o1.z = o1.z > 0.f ? o1.z : 0.f;  o1.w = o1.w > 0.f ? o1.w : 0.f;
        float4* op = (float4*)&xout[(size_t)d * HID + l * 8];
        op[0] = o0;
        op[1] = o1;
    }
}

// ---------------- pooling + MLP ----------------

__global__ void pool_sum(const float* __restrict__ x, int n, float* __restrict__ g) {
    __shared__ float sm[256];
    int t = threadIdx.x;
    int c = t & 31;
    int r = t >> 5;   // 8 node-rows per block
    float acc = 0.f;
    for (int i = blockIdx.x * 8 + r; i < n; i += gridDim.x * 8)
        acc += x[(size_t)i * HID + c];
    sm[t] = acc;
    __syncthreads();
    if (t < 32) {
        float v = 0.f;
#pragma unroll
        for (int k = 0; k < 8; k++) v += sm[t + 32 * k];
        atomicAdd(&g[t], v);
    }
}

__global__ void mlp_final(const float* __restrict__ g,
                          const float* __restrict__ lw1, const float* __restrict__ lb1,
                          const float* __restrict__ lw2, const float* __restrict__ lb2,
                          float* __restrict__ out, float invn) {
    __shared__ float gm[32];
    int t = threadIdx.x;
    if (t < 32) gm[t] = g[t] * invn;
    __syncthreads();
    float q = 0.f;
    if (t < 16) {
        q = lb1[t];
        for (int c = 0; c < 32; c++) q += gm[c] * lw1[c * 16 + t];
        q = q > 0.f ? q : 0.f;
        q *= lw2[t];
    }
#pragma unroll
    for (int off = 8; off >= 1; off >>= 1) q += __shfl_xor(q, off);
    if (t == 0) out[0] = q + lb2[0];
}

// ---------------- launch ----------------

extern "C" void kernel_launch(void* const* d_in, const int* in_sizes, int n_in,
                              void* d_out, int out_size, void* d_ws, size_t ws_size,
                              hipStream_t stream) {
    const float* x   = (const float*)d_in[0];
    const int*   ei  = (const int*)d_in[1];
    const float* W1  = (const float*)d_in[2];
    const float* as1 = (const float*)d_in[3];
    const float* ad1 = (const float*)d_in[4];
    const float* b1  = (const float*)d_in[5];
    const float* W2  = (const float*)d_in[6];
    const float* as2 = (const float*)d_in[7];
    const float* ad2 = (const float*)d_in[8];
    const float* b2  = (const float*)d_in[9];
    const float* W3  = (const float*)d_in[10];
    const float* as3 = (const float*)d_in[11];
    const float* ad3 = (const float*)d_in[12];
    const float* b3  = (const float*)d_in[13];
    const float* lw1 = (const float*)d_in[14];
    const float* lb1 = (const float*)d_in[15];
    const float* lw2 = (const float*)d_in[16];
    const float* lb2 = (const float*)d_in[17];
    float* out = (float*)d_out;

    int n = in_sizes[0] / 128;   // 100000
    int E = in_sizes[1] / 2;     // 1600000
    int nb = (n + 31) >> BSHIFT; // 3125 buckets

    // workspace carve (256B aligned)
    char* p = (char*)d_ws;
    auto alloc = [&](size_t bytes) -> void* {
        void* r = (void*)p;
        p += (bytes + 255) & ~(size_t)255;
        return r;
    };
    int* deg       = (int*)alloc((size_t)n * 4);
    int* row_start = (int*)alloc((size_t)n * 4);
    int* bcnt      = (int*)alloc((size_t)nb * 4);
    int* gbase     = (int*)alloc((size_t)(nb + 1) * 4);
    int* gcursor   = (int*)alloc((size_t)nb * 4);
    int* csr       = (int*)alloc((size_t)E * 4);
    uint32_t* tmp  = (uint32_t*)alloc((size_t)E * 4);
    float* asrc    = (float*)alloc((size_t)n * HEADS * 4);
    float* adst    = (float*)alloc((size_t)n * HEADS * 4);
    uint32_t* hb   = (uint32_t*)alloc((size_t)n * 64 * 4);   // bf16x2 packed h (256B rows)
    float* xA      = (float*)alloc((size_t)n * HID * 4);
    float* xB      = (float*)alloc((size_t)n * HID * 4);
    float* g       = (float*)alloc(32 * 4);
    unsigned short* wbt = (unsigned short*)alloc((size_t)144 * 136 * 2);  // padded bf16 W^T (+wasd)

    // CSR build (bucket-granular, shared across all 3 layers)
    hipMemsetAsync(bcnt, 0, (size_t)nb * 4, stream);
    bucket_hist<<<256, 256, 0, stream>>>(ei, E, nb, bcnt);
    bucket_scan<<<1, 512, 0, stream>>>(bcnt, nb, gbase, gcursor);
    bucket_scatter<<<256, 512, 0, stream>>>(ei, E, nb, gcursor, tmp);
    bucket_sort<<<nb, 256, 0, stream>>>(tmp, gbase, n, csr, row_start, deg);

    int gb = (n + 63) / 64;
    int ggb = (n + 3) / 4;
    int wg128 = (144 * 136 + 255) / 256;
    int wg32  = (144 * 40 + 255) / 256;

    // layer 1
    prep_w<128><<<wg128, 256, 0, stream>>>(W1, as1, ad1, wbt);
    gemm_mfma<128><<<gb, 256, 0, stream>>>(x, wbt, hb, asrc, adst, n);
    aggregate<<<ggb, 256, 0, stream>>>(hb, asrc, adst, row_start, deg, csr, b1, xA, n);

    // layer 2
    prep_w<32><<<wg32, 256, 0, stream>>>(W2, as2, ad2, wbt);
    gemm_mfma<32><<<gb, 256, 0, stream>>>(xA, wbt, hb, asrc, adst, n);
    aggregate<<<ggb, 256, 0, stream>>>(hb, asrc, adst, row_start, deg, csr, b2, xB, n);

    // layer 3
    prep_w<32><<<wg32, 256, 0, stream>>>(W3, as3, ad3, wbt);
    gemm_mfma<32><<<gb, 256, 0, stream>>>(xB, wbt, hb, asrc, adst, n);
    aggregate<<<ggb, 256, 0, stream>>>(hb, asrc, adst, row_start, deg, csr, b3, xA, n);

    // pooling + MLP
    hipMemsetAsync(g, 0, 32 * 4, stream);
    pool_sum<<<256, 256, 0, stream>>>(xA, n, g);
    mlp_final<<<1, 64, 0, stream>>>(g, lw1, lb1, lw2, lb2, out, 1.0f / (float)n);
}